// Round 1
// baseline (858.686 us; speedup 1.0000x reference)
//
#include <hip/hip_runtime.h>
#include <hip/hip_fp16.h>

typedef _Float16 f16;
typedef _Float16 half8  __attribute__((ext_vector_type(8)));
typedef _Float16 half4v __attribute__((ext_vector_type(4)));
typedef _Float16 half2v __attribute__((ext_vector_type(2)));
typedef float    floatx4 __attribute__((ext_vector_type(4)));

constexpr int SEQ  = 4096;   // L
constexpr int SEQP = 4098;   // L + 2 (zero pad row at each end per batch)

// ---------------------------------------------------------------------------
// async global->LDS, 16B per lane. ldsBase+off must be the WAVE-UNIFORM base;
// HW writes lane i to base + i*16. [learn_hip m97/m104]
__device__ __forceinline__ void dma16(const void* g, char* ldsBase, unsigned off) {
  __builtin_amdgcn_global_load_lds(
      (const __attribute__((address_space(1))) void*)g,
      (__attribute__((address_space(3))) void*)(ldsBase + off),
      16, 0, 0);
}

// ---------------------------------------------------------------------------
// GEMM over conv windows: C[r, n] = sum_k A[r, k] * W[k, n] + bias[n]
// A row r = contiguous 3*Cin window starting at padded row (r % SEQ), i.e.
//   A_elem(r, k) = Aact[b*batchStrideA + (l0+r)*lda + k],  lda = Cin.
// Wt is W transposed: [N, K] row-major fp16.
// EPI: 0 = store f16, 1 = swish -> f16, 2 = store f32
template <int EPI>
__global__ __launch_bounds__(256, 2)
void gemm_k(const f16* __restrict__ A, const f16* __restrict__ Wt,
            const float* __restrict__ bias, void* __restrict__ Cp,
            int K, int lda, long batchStrideA,
            int ldc, long batchStrideC, int rowOff)
{
  __shared__ f16 lds[8192];          // A tile [128][32] | B tile [128][32]
  char* ldsB = (char*)lds;

  const int tid  = threadIdx.x;
  const int lane = tid & 63;
  const int wv   = tid >> 6;
  const int quad = lane >> 4;
  const int lr   = lane & 15;
  const int w_row = wv >> 1, w_col = wv & 1;

  const int r0 = blockIdx.x * 128;
  const int n0 = blockIdx.y * 128;
  const int b  = r0 >> 12;           // SEQ = 4096
  const int l0 = r0 & (SEQ - 1);

  const f16* Ab = A + (long)b * batchStrideA + (long)l0 * lda;

  // staging: 512 chunks of 16B per tile; this thread owns chunks tid, tid+256
  const int c0 = tid, c1 = tid + 256;
  const f16* gA0 = Ab + (long)(c0 >> 2) * lda + (c0 & 3) * 8;
  const f16* gA1 = Ab + (long)(c1 >> 2) * lda + (c1 & 3) * 8;
  const f16* gB0 = Wt + (long)(n0 + (c0 >> 2)) * K + (c0 & 3) * 8;
  const f16* gB1 = Wt + (long)(n0 + (c1 >> 2)) * K + (c1 & 3) * 8;
  const unsigned la0 = wv * 1024;            // wave-uniform LDS bases
  const unsigned la1 = 4096  + wv * 1024;
  const unsigned lb0 = 8192  + wv * 1024;
  const unsigned lb1 = 12288 + wv * 1024;

  floatx4 acc[4][4];
#pragma unroll
  for (int mi = 0; mi < 4; mi++)
#pragma unroll
    for (int ni = 0; ni < 4; ni++) acc[mi][ni] = (floatx4){0.f, 0.f, 0.f, 0.f};

  for (int k0 = 0; k0 < K; k0 += 32) {
    __syncthreads();                 // previous iteration's reads done
    dma16(gA0 + k0, ldsB, la0);
    dma16(gA1 + k0, ldsB, la1);
    dma16(gB0 + k0, ldsB, lb0);
    dma16(gB1 + k0, ldsB, lb1);
    __syncthreads();                 // drains vmcnt, publishes LDS

    half8 af[4], bf[4];
#pragma unroll
    for (int mi = 0; mi < 4; mi++)
      af[mi] = *(const half8*)&lds[(w_row * 64 + mi * 16 + lr) * 32 + quad * 8];
#pragma unroll
    for (int ni = 0; ni < 4; ni++)
      bf[ni] = *(const half8*)&lds[4096 + (w_col * 64 + ni * 16 + lr) * 32 + quad * 8];

#pragma unroll
    for (int mi = 0; mi < 4; mi++)
#pragma unroll
      for (int ni = 0; ni < 4; ni++)
        acc[mi][ni] = __builtin_amdgcn_mfma_f32_16x16x32_f16(af[mi], bf[ni], acc[mi][ni], 0, 0, 0);
  }

  // epilogue: C/D layout col=lane&15, row=quad*4+reg  [learn_hip m89]
  const int colBase = n0 + w_col * 64 + lr;
  float bv[4];
#pragma unroll
  for (int ni = 0; ni < 4; ni++) bv[ni] = bias[colBase + ni * 16];

  const long cbb = (long)b * batchStrideC;
#pragma unroll
  for (int mi = 0; mi < 4; mi++) {
#pragma unroll
    for (int i = 0; i < 4; i++) {
      const int rl = w_row * 64 + mi * 16 + quad * 4 + i;
      const long rowFlat = cbb + (long)(l0 + rl + rowOff) * ldc;
#pragma unroll
      for (int ni = 0; ni < 4; ni++) {
        float v = acc[mi][ni][i] + bv[ni];
        if (EPI == 1) v = v / (1.f + expf(-v));           // swish
        if (EPI == 2) ((float*)Cp)[rowFlat + colBase + ni * 16] = v;
        else          ((f16*)Cp)[rowFlat + colBase + ni * 16] = (f16)v;
      }
    }
  }
}

// ---------------------------------------------------------------------------
// weight transpose+convert: w [K,N] f32 -> wt [N,K] f16 (LDS-tiled, coalesced)
__global__ __launch_bounds__(256)
void wt_transpose(const float* __restrict__ w, f16* __restrict__ wt, int K, int N)
{
  __shared__ float tile[32][33];
  const int kt = blockIdx.x * 32, nt = blockIdx.y * 32;
  const int tx = threadIdx.x & 31, ty = threadIdx.x >> 5;
#pragma unroll
  for (int i = 0; i < 32; i += 8)
    tile[ty + i][tx] = w[(long)(kt + ty + i) * N + nt + tx];
  __syncthreads();
#pragma unroll
  for (int i = 0; i < 32; i += 8)
    wt[(long)(nt + ty + i) * K + kt + tx] = (f16)tile[tx][ty + i];
}

// fc2|fc3 concat, zero-padded to 128 cols, transposed: wt [128, 3072] f16
__global__ void fc23_build(const float* __restrict__ fc2, const float* __restrict__ fc3,
                           f16* __restrict__ wt)
{
  int idx = blockIdx.x * 256 + threadIdx.x;   // over 128*3072
  int n = idx / 3072, k = idx - n * 3072;
  float v = 0.f;
  if (n < 16)      v = fc2[k * 16 + n];
  else if (n < 32) v = fc3[k * 16 + n - 16];
  wt[idx] = (f16)v;
}

__global__ void fc23_bias(const float* __restrict__ b2, const float* __restrict__ b3,
                          float* __restrict__ bo)
{
  int t = threadIdx.x;
  if (t < 128) bo[t] = t < 16 ? b2[t] : (t < 32 ? b3[t - 16] : 0.f);
}

// zero the padding rows (p=0 and p=SEQP-1 per batch) of the 4 padded buffers
__global__ void zero_pads(f16* xn, f16* xproj, f16* xconv, f16* xco)
{
  int b = blockIdx.x >> 1, e = blockIdx.x & 1;
  f16* base; int C;
  switch (blockIdx.y) {
    case 0:  base = xn;    C = 512;  break;
    case 1:  base = xproj; C = 1024; break;
    case 2:  base = xconv; C = 1024; break;
    default: base = xco;   C = 1024; break;
  }
  long p = e ? (SEQP - 1) : 0;
  f16* row = base + ((long)b * SEQP + p) * C;
  for (int c = threadIdx.x; c < C; c += 256) row[c] = (f16)0;
}

// rmsnorm over D=512, fp32 in -> fp16 padded out
__global__ __launch_bounds__(256)
void rmsnorm_k(const float* __restrict__ x, const float* __restrict__ nw,
               f16* __restrict__ xn)
{
  const int row = blockIdx.x;             // 0..16383
  const int b = row >> 12, l = row & (SEQ - 1);
  const int t = threadIdx.x;
  float2 v = ((const float2*)(x + (long)row * 512))[t];
  float ss = v.x * v.x + v.y * v.y;
#pragma unroll
  for (int o = 32; o > 0; o >>= 1) ss += __shfl_down(ss, o, 64);
  __shared__ float sred[4];
  if ((t & 63) == 0) sred[t >> 6] = ss;
  __syncthreads();
  float tot = sred[0] + sred[1] + sred[2] + sred[3];
  float rs = rsqrtf(tot * (1.f / 512.f) + 1e-5f);
  float2 w = ((const float2*)nw)[t];
  half2v o2;
  o2.x = (f16)(v.x * rs * w.x);
  o2.y = (f16)(v.y * rs * w.y);
  ((half2v*)(xn + ((long)b * SEQP + l + 1) * 512))[t] = o2;
}

// x_ssm * x_res:  prod = xco * softplus(delta_pre) * (sum_16 Cm*Bm) * xres
__global__ __launch_bounds__(256)
void combine_k(const f16* __restrict__ delta_pre, const f16* __restrict__ xco_pad,
               const f16* __restrict__ bmcm, const f16* __restrict__ xres,
               f16* __restrict__ prod_pad)
{
  const int row = blockIdx.x;
  const int b = row >> 12, l = row & (SEQ - 1);
  const int t = threadIdx.x;
  __shared__ float cb_s;
  if (t < 16) {
    float bmv = (float)bmcm[(long)row * 128 + t];
    float cmv = (float)bmcm[(long)row * 128 + 16 + t];
    float p = bmv * cmv;
#pragma unroll
    for (int o = 8; o > 0; o >>= 1) p += __shfl_down(p, o, 64);
    if (t == 0) cb_s = p;
  }
  __syncthreads();
  const float cb = cb_s;
  const long urow = (long)row * 1024;
  const long prow = ((long)b * SEQP + l + 1) * 1024;
  half4v dp = ((const half4v*)(delta_pre + urow))[t];
  half4v xc = ((const half4v*)(xco_pad + prow))[t];
  half4v xr = ((const half4v*)(xres + urow))[t];
  half4v o;
#pragma unroll
  for (int j = 0; j < 4; j++) {
    float d  = (float)dp[j];
    float sp = d > 20.f ? d : log1pf(expf(d));     // softplus
    o[j] = (f16)((float)xc[j] * sp * cb * (float)xr[j]);
  }
  ((half4v*)(prod_pad + prow))[t] = o;
}

// ---------------------------------------------------------------------------
extern "C" void kernel_launch(void* const* d_in, const int* in_sizes, int n_in,
                              void* d_out, int out_size, void* d_ws, size_t ws_size,
                              hipStream_t stream)
{
  const float* x      = (const float*)d_in[0];
  const float* norm_w = (const float*)d_in[1];
  const float* inp_w  = (const float*)d_in[2];
  const float* inp_b  = (const float*)d_in[3];
  const float* conv_w = (const float*)d_in[4];
  const float* conv_b = (const float*)d_in[5];
  const float* cl_w   = (const float*)d_in[6];
  const float* cl_b   = (const float*)d_in[7];
  const float* fc1_w  = (const float*)d_in[8];
  const float* fc1_b  = (const float*)d_in[9];
  const float* fc2_w  = (const float*)d_in[10];
  const float* fc2_b  = (const float*)d_in[11];
  const float* fc3_w  = (const float*)d_in[12];
  const float* fc3_b  = (const float*)d_in[13];
  // d_in[14] = A: provably unused (dA multiplies a zero initial state)
  const float* res_w  = (const float*)d_in[15];
  const float* res_b  = (const float*)d_in[16];
  const float* out_w  = (const float*)d_in[17];
  const float* out_b  = (const float*)d_in[18];

  char* ws = (char*)d_ws;
  size_t off = 0;
  auto alloc = [&](size_t bytes) -> char* {
    char* p = ws + off; off += (bytes + 511) & ~(size_t)511; return p;
  };
  f16* Wt_inp   = (f16*)alloc(1024ull * 1536 * 2);
  f16* Wt_conv  = (f16*)alloc(1024ull * 3072 * 2);
  f16* Wt_cl    = (f16*)alloc(1024ull * 3072 * 2);
  f16* Wt_fc1   = (f16*)alloc(1024ull * 3072 * 2);
  f16* Wt_fc23  = (f16*)alloc(128ull  * 3072 * 2);
  f16* Wt_res   = (f16*)alloc(1024ull * 1536 * 2);
  f16* Wt_out   = (f16*)alloc(512ull  * 3072 * 2);
  float* b_fc23 = (float*)alloc(128 * 4);
  f16* xn_pad    = (f16*)alloc(4ull * SEQP * 512  * 2);
  f16* xproj_pad = (f16*)alloc(4ull * SEQP * 1024 * 2);  // later reused as prod_pad
  f16* xconv_pad = (f16*)alloc(4ull * SEQP * 1024 * 2);  // later reused as delta_pre
  f16* xco_pad   = (f16*)alloc(4ull * SEQP * 1024 * 2);
  f16* bmcm      = (f16*)alloc(16384ull * 128  * 2);
  f16* xres      = (f16*)alloc(16384ull * 1024 * 2);
  // total ~184.3 MB

  // --- weight prep (reruns every launch: ws is re-poisoned) ---
  wt_transpose<<<dim3(1536 / 32, 1024 / 32), 256, 0, stream>>>(inp_w,  Wt_inp,  1536, 1024);
  wt_transpose<<<dim3(3072 / 32, 1024 / 32), 256, 0, stream>>>(conv_w, Wt_conv, 3072, 1024);
  wt_transpose<<<dim3(3072 / 32, 1024 / 32), 256, 0, stream>>>(cl_w,   Wt_cl,   3072, 1024);
  wt_transpose<<<dim3(3072 / 32, 1024 / 32), 256, 0, stream>>>(fc1_w,  Wt_fc1,  3072, 1024);
  wt_transpose<<<dim3(1536 / 32, 1024 / 32), 256, 0, stream>>>(res_w,  Wt_res,  1536, 1024);
  wt_transpose<<<dim3(3072 / 32,  512 / 32), 256, 0, stream>>>(out_w,  Wt_out,  3072, 512);
  fc23_build<<<1536, 256, 0, stream>>>(fc2_w, fc3_w, Wt_fc23);
  fc23_bias<<<1, 128, 0, stream>>>(fc2_b, fc3_b, b_fc23);
  zero_pads<<<dim3(8, 4), 256, 0, stream>>>(xn_pad, xproj_pad, xconv_pad, xco_pad);

  // --- pipeline ---
  rmsnorm_k<<<16384, 256, 0, stream>>>(x, norm_w, xn_pad);

  // x_proj = conv(xn, inp)                      [K=1536 -> N=1024, padded out]
  gemm_k<0><<<dim3(128, 8), 256, 0, stream>>>(xn_pad, Wt_inp, inp_b, xproj_pad,
      1536, 512, (long)SEQP * 512, 1024, (long)SEQP * 1024, 1);
  // x_conv = swish(conv(x_proj, conv))          [3072 -> 1024, padded]
  gemm_k<1><<<dim3(128, 8), 256, 0, stream>>>(xproj_pad, Wt_conv, conv_b, xconv_pad,
      3072, 1024, (long)SEQP * 1024, 1024, (long)SEQP * 1024, 1);
  // x_conv_out = conv(x_conv, cl)               [3072 -> 1024, padded]
  gemm_k<0><<<dim3(128, 8), 256, 0, stream>>>(xconv_pad, Wt_cl, cl_b, xco_pad,
      3072, 1024, (long)SEQP * 1024, 1024, (long)SEQP * 1024, 1);
  // delta_pre = conv(xco, fc1)                  [3072 -> 1024, unpadded; aliases xconv]
  f16* delta_pre = xconv_pad;
  gemm_k<0><<<dim3(128, 8), 256, 0, stream>>>(xco_pad, Wt_fc1, fc1_b, delta_pre,
      3072, 1024, (long)SEQP * 1024, 1024, (long)SEQ * 1024, 0);
  // [Bm|Cm] = conv(xco, fc2|fc3 padded to 128)  [3072 -> 128, unpadded]
  gemm_k<0><<<dim3(128, 1), 256, 0, stream>>>(xco_pad, Wt_fc23, b_fc23, bmcm,
      3072, 1024, (long)SEQP * 1024, 128, (long)SEQ * 128, 0);
  // x_res = swish(conv(xn, res))                [1536 -> 1024, unpadded]
  gemm_k<1><<<dim3(128, 8), 256, 0, stream>>>(xn_pad, Wt_res, res_b, xres,
      1536, 512, (long)SEQP * 512, 1024, (long)SEQ * 1024, 0);
  // prod = x_ssm * x_res                        [padded; aliases xproj]
  f16* prod_pad = xproj_pad;
  combine_k<<<16384, 256, 0, stream>>>(delta_pre, xco_pad, bmcm, xres, prod_pad);
  // out = conv(prod, out)                       [3072 -> 512, fp32 -> d_out]
  gemm_k<2><<<dim3(128, 4), 256, 0, stream>>>(prod_pad, Wt_out, out_b, d_out,
      3072, 1024, (long)SEQP * 1024, 512, (long)SEQ * 512, 0);
}